// Round 5
// baseline (94.486 us; speedup 1.0000x reference)
//
#include <hip/hip_runtime.h>
#include <math.h>

// N=8192, M=64, K=256, D=16
#define M_SUB 64
#define K_CODES 256
#define D_DIM 16
#define ROW_F 1024            // floats per vecs/out row
#define THRGAP 0.0078125f     // top-2 gap below this -> exact fp64 fixup
#define YS 8                  // m-groups in grid.y
#define MPB (M_SUB / YS)      // 8 m per block
#define NRB 128               // rows per block (8 waves x 16)
#define SLICE_B 21504         // packed bytes per m-slice: 256*80 (codes) + 1024 (NC2)
#define BLDS_B 20480

typedef __attribute__((ext_vector_type(8))) short short8;
typedef __attribute__((ext_vector_type(4))) float f32x4;

// ---- bf16 RNE split helpers (bit-identical to R4's verified path) ----
__device__ inline unsigned bfr(float x) {
    unsigned u = __builtin_bit_cast(unsigned, x);
    return (u + 0x7FFFu + ((u >> 16) & 1u)) >> 16;
}
__device__ inline float bff(unsigned h) { return __builtin_bit_cast(float, h << 16); }

// ---- DPP 16-lane-row reduce helpers (proven R3/R4) ----
template <int C> __device__ inline float dppf(float x) {
    return __builtin_bit_cast(float,
        __builtin_amdgcn_update_dpp(0, __builtin_bit_cast(int, x), C, 0xF, 0xF, true));
}
template <int C> __device__ inline int dppi(int x) {
    return __builtin_amdgcn_update_dpp(0, x, C, 0xF, 0xF, true);
}

// ---- async global->LDS (linear dest = wave-uniform base + lane*size) ----
__device__ inline void gl_lds16(const void* g, void* l) {
    __builtin_amdgcn_global_load_lds((const __attribute__((address_space(1))) void*)g,
                                     (__attribute__((address_space(3))) void*)l, 16, 0, 0);
}
__device__ inline void gl_lds4(const void* g, void* l) {
    __builtin_amdgcn_global_load_lds((const __attribute__((address_space(1))) void*)g,
                                     (__attribute__((address_space(3))) void*)l, 4, 0, 0);
}

// =============== k0: one-time codebook convert (bit-identical math) ==========
__global__ __launch_bounds__(256) void pq_convert_kernel(
    const float* __restrict__ cb, char* __restrict__ pk, unsigned* __restrict__ meta)
{
    const int m = blockIdx.x, k = threadIdx.x;
    if (m == 0 && k == 0) meta[0] = 0;                  // zero fixup counter
    const float* cp = cb + ((size_t)m * K_CODES + k) * D_DIM;
    float f[16];
    #pragma unroll
    for (int q = 0; q < 4; ++q) {
        float4 t4 = ((const float4*)cp)[q];
        f[q*4+0] = t4.x; f[q*4+1] = t4.y; f[q*4+2] = t4.z; f[q*4+3] = t4.w;
    }
    float c2 = 0.f;
    #pragma unroll
    for (int d = 0; d < 16; ++d) c2 = fmaf(f[d], f[d], c2);
    short hi[16], lo[16];
    #pragma unroll
    for (int d = 0; d < 16; ++d) {
        unsigned h = bfr(f[d]);
        hi[d] = (short)h;
        lo[d] = (short)bfr(f[d] - bff(h));
    }
    char* base = pk + (size_t)m * SLICE_B + k * 80;     // 80 B/code: 64 data + 16 pad
    short8 v0 = { hi[0],hi[1],hi[2],hi[3],hi[4],hi[5],hi[6],hi[7] };
    short8 v1 = { hi[8],hi[9],hi[10],hi[11],hi[12],hi[13],hi[14],hi[15] };
    short8 v2 = { lo[0],lo[1],lo[2],lo[3],lo[4],lo[5],lo[6],lo[7] };
    short8 v3 = { lo[8],lo[9],lo[10],lo[11],lo[12],lo[13],lo[14],lo[15] };
    *(short8*)(base +  0) = v0; *(short8*)(base + 16) = v1;
    *(short8*)(base + 32) = v2; *(short8*)(base + 48) = v3;
    *(float*)(pk + (size_t)m * SLICE_B + BLDS_B + k * 4) = -c2;
}

// stage one packed m-slice into an LDS buffer (512 threads = 8 waves)
__device__ inline void stage_slice(const char* g, char* lbuf, int tid, int w) {
    gl_lds16(g + tid * 16,          lbuf + w * 1024);            // [0, 8192)
    gl_lds16(g + 8192 + tid * 16,   lbuf + 8192 + w * 1024);     // [8192, 16384)
    if (tid < 256) {                                             // wave-uniform branch
        gl_lds16(g + 16384 + tid * 16, lbuf + 16384 + w * 1024); // [16384, 20480)
        gl_lds4 (g + BLDS_B + tid * 4, lbuf + BLDS_B + w * 256); // NC2 [20480, 21504)
    }
}

// ===================== k1: MFMA scores + argmax =====================
// Fragment roles / numerics byte-identical to the PASSING R4 kernel.
__global__ __launch_bounds__(512, 4) void pq_mfma_kernel(
    const float* __restrict__ vecs, const float* __restrict__ cb,
    float* __restrict__ out, const char* __restrict__ pk,
    unsigned* __restrict__ meta, unsigned cap)
{
    const int m0  = blockIdx.y * MPB;
    const int nb  = blockIdx.x * NRB;
    const int tid = threadIdx.x;
    const int w    = tid >> 6;
    const int lane = tid & 63;
    const int lr   = lane & 15;
    const int lg   = lane >> 4;

    __shared__ __align__(16) char BUF[2][SLICE_B];   // double-buffered slice image
    __shared__ unsigned IDXs[MPB * 32];              // winner k per (mi, 4-row group)

    unsigned* cnt  = meta;
    unsigned* list = meta + 1;

    const float* vbaseA = vecs + (size_t)(nb + w * 16 + lr) * ROW_F + (lg & 1) * 8;
    const char* pkm = pk + (size_t)m0 * SLICE_B;

    stage_slice(pkm, BUF[0], tid, w);
    __syncthreads();

    #pragma unroll 1
    for (int mi = 0; mi < MPB; ++mi) {
        const int cur = mi & 1;
        // A loads first (complete early), then prefetch next slice async
        const float* vp = vbaseA + (size_t)(m0 + mi) * D_DIM;
        float4 a4 = ((const float4*)vp)[0];
        float4 b4 = ((const float4*)vp)[1];
        if (mi + 1 < MPB) stage_slice(pkm + (size_t)(mi + 1) * SLICE_B, BUF[cur ^ 1], tid, w);

        // ---- A conversion (identical math: scale 2, bf16 hi/lo split) ----
        float f[8];
        f[0]=2.f*a4.x; f[1]=2.f*a4.y; f[2]=2.f*a4.z; f[3]=2.f*a4.w;
        f[4]=2.f*b4.x; f[5]=2.f*b4.y; f[6]=2.f*b4.z; f[7]=2.f*b4.w;
        short hi[8], lo[8];
        #pragma unroll
        for (int e = 0; e < 8; ++e) {
            unsigned h = bfr(f[e]);
            hi[e] = (short)h;
            lo[e] = (short)bfr(f[e] - bff(h));
        }
        short8 H = { hi[0],hi[1],hi[2],hi[3],hi[4],hi[5],hi[6],hi[7] };
        short8 L = { lo[0],lo[1],lo[2],lo[3],lo[4],lo[5],lo[6],lo[7] };
        const bool hiSide = (lg < 2);
        short8 A1 = hiSide ? H : L;
        short8 A2 = hiSide ? L : H;

        const short* Bb = (const short*)BUF[cur];
        const float* NC = (const float*)(BUF[cur] + BLDS_B);

        // ---- scores (identical: C-init = -c2, MFMA(A1) then MFMA(A2)) ----
        f32x4 acc[16];
        #pragma unroll
        for (int kt = 0; kt < 16; ++kt) {
            short8 B = *(const short8*)&Bb[(kt * 16 + lr) * 40 + lg * 8];
            float nv = NC[kt * 16 + lr];
            f32x4 c0 = { nv, nv, nv, nv };
            c0 = __builtin_amdgcn_mfma_f32_16x16x32_bf16(A1, B, c0, 0, 0, 0);
            c0 = __builtin_amdgcn_mfma_f32_16x16x32_bf16(A2, B, c0, 0, 0, 0);
            acc[kt] = c0;
        }

        // ---- argmax: max3 tree -> DPP max -> candidate bitmask ----
        unsigned kp[4]; unsigned fl = 0;
        #pragma unroll
        for (int p = 0; p < 4; ++p) {          // row = lg*4 + p
            float x0 = fmaxf(fmaxf(acc[0][p],  acc[1][p]),  acc[2][p]);
            float x1 = fmaxf(fmaxf(acc[3][p],  acc[4][p]),  acc[5][p]);
            float x2 = fmaxf(fmaxf(acc[6][p],  acc[7][p]),  acc[8][p]);
            float x3 = fmaxf(fmaxf(acc[9][p],  acc[10][p]), acc[11][p]);
            float x4 = fmaxf(fmaxf(acc[12][p], acc[13][p]), acc[14][p]);
            float b  = fmaxf(fmaxf(fmaxf(x0, x1), x2), fmaxf(fmaxf(x3, x4), acc[15][p]));
            b = fmaxf(b, dppf<0xB1>(b));
            b = fmaxf(b, dppf<0x4E>(b));
            b = fmaxf(b, dppf<0x141>(b));
            b = fmaxf(b, dppf<0x140>(b));      // full 16-lane row max
            const float bthr = b - THRGAP;
            unsigned Mm = 0;
            #pragma unroll
            for (int kt = 15; kt >= 0; --kt)   // bit kt = candidate flag
                Mm = Mm + Mm + (acc[kt][p] >= bthr ? 1u : 0u);
            int cl  = __popc(Mm);
            int bkt = __ffs(Mm) - 1;           // lowest candidate kt in lane (or -1)
            int bkv = Mm ? (bkt * 16 + lr) : 0x7FFFFFFF;
            cl += dppi<0xB1>(cl);  bkv = min(bkv, dppi<0xB1>(bkv));
            cl += dppi<0x4E>(cl);  bkv = min(bkv, dppi<0x4E>(bkv));
            cl += dppi<0x141>(cl); bkv = min(bkv, dppi<0x141>(bkv));
            cl += dppi<0x140>(cl); bkv = min(bkv, dppi<0x140>(bkv));
            kp[p] = (unsigned)bkv & 255u;
            fl |= (cl != 1) ? (1u << p) : 0u;  // tie/near-tie -> exact fp64 pass
        }
        if (lr == 0) {
            IDXs[mi * 32 + w * 4 + lg] = kp[0] | (kp[1] << 8) | (kp[2] << 16) | (kp[3] << 24);
            if (fl) {
                #pragma unroll
                for (int p = 0; p < 4; ++p) if (fl & (1u << p)) {
                    unsigned idx = atomicAdd(cnt, 1u);
                    if (idx < cap)
                        list[idx] = ((unsigned)(nb + w * 16 + lg * 4 + p) << 6) | (unsigned)(m0 + mi);
                }
            }
        }
        __syncthreads();   // drains prefetch (issued a full phase ago) + LDS ops
    }

    // ---- coalesced epilogue: each row's 512-B m-chunk written contiguously ----
    const int row = tid >> 2, q = tid & 3;
    #pragma unroll
    for (int s = 0; s < 2; ++s) {
        const int mi = q * 2 + s;
        unsigned pk4 = IDXs[mi * 32 + (row >> 2)];
        int k = (int)((pk4 >> ((row & 3) * 8)) & 255u);
        const float4* src = (const float4*)(cb + ((size_t)(m0 + mi) * K_CODES + k) * D_DIM);
        float4* dst = (float4*)(out + (size_t)(nb + row) * ROW_F + (size_t)(m0 + mi) * D_DIM);
        dst[0] = src[0]; dst[1] = src[1]; dst[2] = src[2]; dst[3] = src[3];
    }
}

// ===================== k2: exact fp64 fixup (proven, unchanged) ==============
__global__ __launch_bounds__(256) void pq_fixup_kernel(
    const float* __restrict__ vecs, const float* __restrict__ cb,
    float* __restrict__ out, const unsigned* __restrict__ meta, unsigned cap)
{
    unsigned cnt = meta[0];
    if (cnt > cap) cnt = cap;
    const unsigned nw  = (gridDim.x * blockDim.x) >> 6;
    const unsigned wid = (blockIdx.x * blockDim.x + threadIdx.x) >> 6;
    const int lane = threadIdx.x & 63;

    for (unsigned e = wid; e < cnt; e += nw) {
        unsigned ent = meta[1 + e];
        const int n = (int)(ent >> 6), m = (int)(ent & 63u);
        const float* vrow = vecs + (size_t)n * ROW_F + m * D_DIM;
        double vd[16];
        #pragma unroll
        for (int d = 0; d < 16; ++d) vd[d] = (double)vrow[d];
        double bs = -1e300; int bi = 0;
        #pragma unroll
        for (int j = 0; j < 4; ++j) {
            int k = lane * 4 + j;
            const float* cp = cb + ((size_t)m * K_CODES + k) * D_DIM;
            double vc = 0.0, c2 = 0.0;
            #pragma unroll
            for (int d = 0; d < 16; ++d) {
                double cd = (double)cp[d];
                vc = fma(vd[d], cd, vc);
                c2 = fma(cd, cd, c2);
            }
            double s = 2.0 * vc - c2;
            if (s > bs) { bs = s; bi = k; }
        }
        #pragma unroll
        for (int off = 32; off; off >>= 1) {
            double so = __shfl_xor(bs, off, 64);
            int    ko = __shfl_xor(bi, off, 64);
            if (so > bs || (so == bs && ko < bi)) { bs = so; bi = ko; }
        }
        if (lane < 4) {
            const float4* src = (const float4*)(cb + ((size_t)m * K_CODES + bi) * D_DIM);
            float4* dst = (float4*)(out + (size_t)n * ROW_F + m * D_DIM);
            dst[lane] = src[lane];
        }
    }
}

extern "C" void kernel_launch(void* const* d_in, const int* in_sizes, int n_in,
                              void* d_out, int out_size, void* d_ws, size_t ws_size,
                              hipStream_t stream) {
    const float* vecs = (const float*)d_in[0];
    const float* cb   = (const float*)d_in[1];
    float* out        = (float*)d_out;
    const int n_rows  = in_sizes[0] / ROW_F;                 // 8192

    // ws layout: [0] counter, [1..] fixup list, tail = packed codebook image
    const size_t pk_bytes = (size_t)M_SUB * SLICE_B;         // 1,376,256 B
    size_t pk_off = (ws_size > pk_bytes + 65536)
                        ? ((ws_size - pk_bytes) & ~(size_t)255) : 0;
    char* pk       = (char*)d_ws + pk_off;
    unsigned* meta = (unsigned*)d_ws;
    size_t cap_sz  = pk_off / 4;
    unsigned cap   = cap_sz > 1048576 ? 1048576u
                     : (cap_sz > 8 ? (unsigned)(cap_sz - 8) : 0u);

    pq_convert_kernel<<<M_SUB, 256, 0, stream>>>(cb, pk, meta);
    pq_mfma_kernel<<<dim3(n_rows / NRB, YS), 512, 0, stream>>>(vecs, cb, out, pk, meta, cap);
    pq_fixup_kernel<<<64, 256, 0, stream>>>(vecs, cb, out, meta, cap);
}

// Round 6
// 60.092 us; speedup vs baseline: 1.5724x; 1.5724x over previous
//
#include <hip/hip_runtime.h>
#include <math.h>

// N=8192, M=64, K=256, D=16
#define M_SUB 64
#define K_CODES 256
#define D_DIM 16
#define ROW_F 1024            // floats per vecs/out row
#define THRGAP 0.0078125f     // top-2 gap below this -> exact fp64 fixup
#define TILE_B 1088           // per kt-tile: 1024 B B-fragments + 64 B NC2
#define SLICE_B (16 * TILE_B) // 17408 B per m-slice

typedef __attribute__((ext_vector_type(8))) short short8;
typedef __attribute__((ext_vector_type(4))) float f32x4;

// ---- bf16 RNE split helpers (bit-identical to the verified R3-R5 path) ----
__device__ inline unsigned bfr(float x) {
    unsigned u = __builtin_bit_cast(unsigned, x);
    return (u + 0x7FFFu + ((u >> 16) & 1u)) >> 16;
}
__device__ inline float bff(unsigned h) { return __builtin_bit_cast(float, h << 16); }

// ---- DPP 16-lane-row reduce helpers (proven R3-R5) ----
template <int C> __device__ inline float dppf(float x) {
    return __builtin_bit_cast(float,
        __builtin_amdgcn_update_dpp(0, __builtin_bit_cast(int, x), C, 0xF, 0xF, true));
}
template <int C> __device__ inline int dppi(int x) {
    return __builtin_amdgcn_update_dpp(0, x, C, 0xF, 0xF, true);
}

// =============== k0: codebook -> fragment-major packed image =================
// Per m-slice: 16 kt-tiles. Tile layout: for lane = lg*16+lr, the 16-B chunk at
// lane*16 is chunk lg of code kt*16+lr ([ch d0-7 | ch d8-15 | cl d0-7 | cl d8-15]);
// NC2 (-||c||^2) floats at +1024 + lr*4.
__global__ __launch_bounds__(256) void pq_convert_kernel(
    const float* __restrict__ cb, char* __restrict__ pk)
{
    const int m = blockIdx.x, k = threadIdx.x;
    const float* cp = cb + ((size_t)m * K_CODES + k) * D_DIM;
    float f[16];
    #pragma unroll
    for (int q = 0; q < 4; ++q) {
        float4 t4 = ((const float4*)cp)[q];
        f[q*4+0] = t4.x; f[q*4+1] = t4.y; f[q*4+2] = t4.z; f[q*4+3] = t4.w;
    }
    float c2 = 0.f;
    #pragma unroll
    for (int d = 0; d < 16; ++d) c2 = fmaf(f[d], f[d], c2);
    short hi[16], lo[16];
    #pragma unroll
    for (int d = 0; d < 16; ++d) {
        unsigned h = bfr(f[d]);
        hi[d] = (short)h;
        lo[d] = (short)bfr(f[d] - bff(h));
    }
    char* tb = pk + (size_t)m * SLICE_B + (k >> 4) * TILE_B;
    const int lr = k & 15;
    short8 v0 = { hi[0],hi[1],hi[2],hi[3],hi[4],hi[5],hi[6],hi[7] };
    short8 v1 = { hi[8],hi[9],hi[10],hi[11],hi[12],hi[13],hi[14],hi[15] };
    short8 v2 = { lo[0],lo[1],lo[2],lo[3],lo[4],lo[5],lo[6],lo[7] };
    short8 v3 = { lo[8],lo[9],lo[10],lo[11],lo[12],lo[13],lo[14],lo[15] };
    *(short8*)(tb +   0 + lr * 16) = v0;
    *(short8*)(tb + 256 + lr * 16) = v1;
    *(short8*)(tb + 512 + lr * 16) = v2;
    *(short8*)(tb + 768 + lr * 16) = v3;
    *(float*)(tb + 1024 + lr * 4) = -c2;
}

// ===================== k1: MFMA scores + argmax + inline fixup ===============
// Wave-independent: each wave owns (32 rows, 1 m). No __syncthreads anywhere.
// Fragment roles / score numerics byte-identical to the PASSING R5 kernel.
__global__ __launch_bounds__(256, 2) void pq_mfma_kernel(
    const float* __restrict__ vecs, const float* __restrict__ cb,
    float* __restrict__ out, const char* __restrict__ pk)
{
    const int tid  = threadIdx.x;
    const int w    = tid >> 6;
    const int lane = tid & 63;
    const int lr   = lane & 15;
    const int lg   = lane >> 4;
    const int wid  = blockIdx.x * 4 + w;
    const int m    = wid >> 8;          // 4 waves of a block share m
    const int n0   = (wid & 255) * 32;  // 32 consecutive rows per wave

    __shared__ unsigned IDXW[4][8];     // packed winner k per (t,lg) group of 4 rows
    __shared__ unsigned FLGW[4][8];     // 4-bit flag nibble per group

    const char* pkm = pk + (size_t)m * SLICE_B;

    // ---- hoist NC2 for this lane's columns: nc2v[kt] = -||c_{kt*16+lr}||^2 ----
    float nc2v[16];
    #pragma unroll
    for (int kt = 0; kt < 16; ++kt)
        nc2v[kt] = *(const float*)(pkm + kt * TILE_B + 1024 + lr * 4);

    // ---- A fragments for 2 row-tiles (identical conv: scale 2, bf16 hi/lo) ----
    short8 A1[2], A2[2];
    #pragma unroll
    for (int t = 0; t < 2; ++t) {
        const float* vp = vecs + (size_t)(n0 + t * 16 + lr) * ROW_F + m * D_DIM + (lg & 1) * 8;
        float4 a4 = ((const float4*)vp)[0];
        float4 b4 = ((const float4*)vp)[1];
        float f[8];
        f[0]=2.f*a4.x; f[1]=2.f*a4.y; f[2]=2.f*a4.z; f[3]=2.f*a4.w;
        f[4]=2.f*b4.x; f[5]=2.f*b4.y; f[6]=2.f*b4.z; f[7]=2.f*b4.w;
        short hi[8], lo[8];
        #pragma unroll
        for (int e = 0; e < 8; ++e) {
            unsigned h = bfr(f[e]);
            hi[e] = (short)h;
            lo[e] = (short)bfr(f[e] - bff(h));
        }
        short8 H = { hi[0],hi[1],hi[2],hi[3],hi[4],hi[5],hi[6],hi[7] };
        short8 L = { lo[0],lo[1],lo[2],lo[3],lo[4],lo[5],lo[6],lo[7] };
        const bool hiSide = (lg < 2);
        A1[t] = hiSide ? H : L;
        A2[t] = hiSide ? L : H;
    }

    // ---- scores: acc[t][kt] = (2v)·c - ||c||^2 (C-init=-c2, MFMA(A1),MFMA(A2)) ----
    f32x4 acc[2][16];
    #pragma unroll
    for (int kt = 0; kt < 16; ++kt) {
        short8 B = *(const short8*)(pkm + kt * TILE_B + lane * 16);  // coalesced 1 KB
        float nv = nc2v[kt];
        f32x4 c0 = { nv, nv, nv, nv };
        f32x4 c1 = { nv, nv, nv, nv };
        c0 = __builtin_amdgcn_mfma_f32_16x16x32_bf16(A1[0], B, c0, 0, 0, 0);
        c0 = __builtin_amdgcn_mfma_f32_16x16x32_bf16(A2[0], B, c0, 0, 0, 0);
        c1 = __builtin_amdgcn_mfma_f32_16x16x32_bf16(A1[1], B, c1, 0, 0, 0);
        c1 = __builtin_amdgcn_mfma_f32_16x16x32_bf16(A2[1], B, c1, 0, 0, 0);
        acc[0][kt] = c0;
        acc[1][kt] = c1;
    }

    // ---- argmax per row (R5-verified logic: max tree -> DPP -> candidate mask) ----
    #pragma unroll
    for (int t = 0; t < 2; ++t) {
        unsigned kp[4]; unsigned rf = 0;
        #pragma unroll
        for (int p = 0; p < 4; ++p) {          // row = t*16 + lg*4 + p
            float x0 = fmaxf(fmaxf(acc[t][0][p],  acc[t][1][p]),  acc[t][2][p]);
            float x1 = fmaxf(fmaxf(acc[t][3][p],  acc[t][4][p]),  acc[t][5][p]);
            float x2 = fmaxf(fmaxf(acc[t][6][p],  acc[t][7][p]),  acc[t][8][p]);
            float x3 = fmaxf(fmaxf(acc[t][9][p],  acc[t][10][p]), acc[t][11][p]);
            float x4 = fmaxf(fmaxf(acc[t][12][p], acc[t][13][p]), acc[t][14][p]);
            float b  = fmaxf(fmaxf(fmaxf(x0, x1), x2), fmaxf(fmaxf(x3, x4), acc[t][15][p]));
            b = fmaxf(b, dppf<0xB1>(b));
            b = fmaxf(b, dppf<0x4E>(b));
            b = fmaxf(b, dppf<0x141>(b));
            b = fmaxf(b, dppf<0x140>(b));      // full 16-lane row max
            const float bthr = b - THRGAP;
            unsigned Mm = 0;
            #pragma unroll
            for (int kt = 15; kt >= 0; --kt)
                Mm = Mm + Mm + (acc[t][kt][p] >= bthr ? 1u : 0u);
            int cl  = __popc(Mm);
            int bkt = __ffs(Mm) - 1;
            int bkv = Mm ? (bkt * 16 + lr) : 0x7FFFFFFF;
            cl += dppi<0xB1>(cl);  bkv = min(bkv, dppi<0xB1>(bkv));
            cl += dppi<0x4E>(cl);  bkv = min(bkv, dppi<0x4E>(bkv));
            cl += dppi<0x141>(cl); bkv = min(bkv, dppi<0x141>(bkv));
            cl += dppi<0x140>(cl); bkv = min(bkv, dppi<0x140>(bkv));
            if (bkv > 255) bkv = 0;            // NaN guard (then flagged below)
            kp[p] = (unsigned)bkv;
            rf |= (cl != 1) ? (1u << p) : 0u;  // tie/near-tie -> exact fp64 pass
        }
        if (lr == 0) {
            IDXW[w][t * 4 + lg] = kp[0] | (kp[1] << 8) | (kp[2] << 16) | (kp[3] << 24);
            FLGW[w][t * 4 + lg] = rf;
        }
    }

    // ---- inline exact fp64 fixup for flagged rows (rare, wave-uniform branch) ----
    #pragma unroll 1
    for (int e = 0; e < 8; ++e) {
        unsigned rf = FLGW[w][e];              // LDS broadcast, same for all lanes
        if (rf) {
            #pragma unroll 1
            for (int p = 0; p < 4; ++p) if (rf & (1u << p)) {
                const int r = (e >> 2) * 16 + (e & 3) * 4 + p;
                const int n = n0 + r;
                const float* vrow = vecs + (size_t)n * ROW_F + m * D_DIM;
                double vd[16];
                #pragma unroll
                for (int d = 0; d < 16; ++d) vd[d] = (double)vrow[d];
                double bs = -1e300; int bi = 0;
                #pragma unroll
                for (int j = 0; j < 4; ++j) {  // lane's codes k = lane*4+j, ascending
                    int k = lane * 4 + j;
                    const float* cp = cb + ((size_t)m * K_CODES + k) * D_DIM;
                    double vc = 0.0, c2 = 0.0;
                    #pragma unroll
                    for (int d = 0; d < 16; ++d) {
                        double cd = (double)cp[d];
                        vc = fma(vd[d], cd, vc);
                        c2 = fma(cd, cd, c2);
                    }
                    double s = 2.0 * vc - c2;
                    if (s > bs) { bs = s; bi = k; }
                }
                #pragma unroll
                for (int off = 32; off; off >>= 1) {  // first-index tie-break
                    double so = __shfl_xor(bs, off, 64);
                    int    ko = __shfl_xor(bi, off, 64);
                    if (so > bs || (so == bs && ko < bi)) { bs = so; bi = ko; }
                }
                if (lane == 0) ((char*)&IDXW[w][e])[p] = (char)bi;
            }
        }
    }

    // ---- epilogue: write winning codes (bit-exact fp32 from cb) ----
    #pragma unroll
    for (int s = 0; s < 2; ++s) {
        const int r = s * 16 + (lane >> 2);     // 4 lanes per row
        unsigned e4 = IDXW[w][r >> 2];
        const int k = (int)((e4 >> ((r & 3) * 8)) & 255u);
        const float4* src = (const float4*)(cb + ((size_t)m * K_CODES + k) * D_DIM);
        float4 val = src[lane & 3];
        float4* dst = (float4*)(out + (size_t)(n0 + r) * ROW_F + m * D_DIM);
        dst[lane & 3] = val;
    }
}

extern "C" void kernel_launch(void* const* d_in, const int* in_sizes, int n_in,
                              void* d_out, int out_size, void* d_ws, size_t ws_size,
                              hipStream_t stream) {
    const float* vecs = (const float*)d_in[0];
    const float* cb   = (const float*)d_in[1];
    float* out        = (float*)d_out;
    char* pk          = (char*)d_ws;            // 64 * 17408 = 1,114,112 B

    pq_convert_kernel<<<M_SUB, 256, 0, stream>>>(cb, pk);
    pq_mfma_kernel<<<4096, 256, 0, stream>>>(vecs, cb, out, pk);
}